// Round 2
// baseline (293.881 us; speedup 1.0000x reference)
//
#include <hip/hip_runtime.h>
#include <stdint.h>
#include <stddef.h>

// out[b, p*768+e] = sum_d x[b,d]*W[p,d]*GE[d,e] + bias[p]
// == per-b GEMM: OUT_b(256x768) = (x_b ⊙ W)(256x2000) @ GE(2000x768) + bias
//
// R7 change vs R6: R6's hipLaunchCooperativeKernel was rejected by the
// harness's graph capture (out stayed memset-zero -> absmax 1.59 = max|ref|).
// Same fused single-kernel structure, but plain launch + manual atomic grid
// barrier (device-scope release add + acquire spin on a workspace counter,
// reset per-replay by a capturable 4B hipMemsetAsync node). Co-residency of
// all 768 blocks (3/CU x 256 CU) is resource-guaranteed: 32KB LDS (5/CU by
// LDS), __launch_bounds__(256,3) caps VGPR; no block retires pre-barrier.
// Spin is capped so failure = visible wrong answer, never a hang.
// Phase 2 GEMM body is byte-identical to the verified R5 kernel.
//
// Workspace: xb 64x2048 f16 (262144 B) | Wb 256x2048 f16 (1048576 B) |
// GT 768x2048 f16 (3145728 B) | counter (4 B) = 4,456,452 B total.

#define F_GENES 2000
#define KPAD    2048      // 32 * 64
#define P_PATH  256
#define EMB     768
#define BATCH   64
#define KSTEPS  32        // BK = 64
#define NBLOCKS 768

typedef _Float16 f16x8 __attribute__((ext_vector_type(8)));
typedef float    f32x4 __attribute__((ext_vector_type(4)));

__device__ __forceinline__ unsigned short f2h(float f) {
    union { _Float16 h; unsigned short s; } v; v.h = (_Float16)f; return v.s;
}

__device__ __forceinline__ void gload16(const void* g, void* l) {
    __builtin_amdgcn_global_load_lds((const __attribute__((address_space(1))) void*)g,
                                     (__attribute__((address_space(3))) void*)l,
                                     16, 0, 0);
}

__global__ __launch_bounds__(256, 3)
void fused_kernel(const float* __restrict__ x, const float* __restrict__ w,
                  const float* __restrict__ ge, const float* __restrict__ bias,
                  float* __restrict__ out,
                  unsigned short* __restrict__ xb, unsigned short* __restrict__ wb,
                  unsigned short* __restrict__ GT, unsigned int* __restrict__ cnt) {
    // 32 KB, shared between phase-1b transpose tile (5 KB) and phase-2 Ws/Bs
    __shared__ __align__(16) _Float16 smem[2 * 128 * 64];

    const int tid = threadIdx.x;
    const int bid = blockIdx.x;

    // ---- phase 1a: pack x (64 rows) + W (256 rows) fp32 -> fp16, K-pad 2048 ----
    if (bid < (BATCH + P_PATH)) {
        int gid = bid * 256 + tid;
        int row = gid >> 8;
        int s   = gid & 255;
        int d0  = s * 8;
        const float* src;
        unsigned short* dst;
        if (row < BATCH) { src = x + (size_t)row * F_GENES;           dst = xb + (size_t)row * KPAD; }
        else             { src = w + (size_t)(row - BATCH) * F_GENES; dst = wb + (size_t)(row - BATCH) * KPAD; }
        uint4 ov = make_uint4(0u, 0u, 0u, 0u);
        if (s < 250) {
            float4 v0 = *(const float4*)(src + d0);
            float4 v1 = *(const float4*)(src + d0 + 4);
            unsigned short* os = (unsigned short*)&ov;
            os[0] = f2h(v0.x); os[1] = f2h(v0.y); os[2] = f2h(v0.z); os[3] = f2h(v0.w);
            os[4] = f2h(v1.x); os[5] = f2h(v1.y); os[6] = f2h(v1.z); os[7] = f2h(v1.w);
        }
        *(uint4*)(dst + d0) = ov;
    }

    // ---- phase 1b: GT[n,k] = f16(GE[k,n]), k-padded to 2048 (all 768 blocks) ----
    {
        unsigned short (*tile)[40] = (unsigned short (*)[40])smem;   // [n][k]
        int kt = bid & 63;                       // 64 k-tiles of 32 (kt=63 zeroes the pad)
        int nt = bid >> 6;                       // 12 n-tiles of 64
        int k0 = kt * 32, n0 = nt * 64;
        int kr = tid >> 4;                       // 0..15
        int nc = (tid & 15) * 4;
#pragma unroll
        for (int p = 0; p < 2; ++p) {
            int k = k0 + p * 16 + kr;
            float4 v = make_float4(0.f, 0.f, 0.f, 0.f);
            if (k < F_GENES) v = *(const float4*)(ge + (size_t)k * EMB + n0 + nc);
            int kk = p * 16 + kr;
            tile[nc + 0][kk] = f2h(v.x);
            tile[nc + 1][kk] = f2h(v.y);
            tile[nc + 2][kk] = f2h(v.z);
            tile[nc + 3][kk] = f2h(v.w);
        }
        __syncthreads();
        int n  = tid >> 2;
        int kc = (tid & 3) * 8;
        uint4 o;
        unsigned short* os = (unsigned short*)&o;
#pragma unroll
        for (int j = 0; j < 8; ++j) os[j] = tile[n][kc + j];
        *(uint4*)(GT + (size_t)(n0 + n) * KPAD + k0 + kc) = o;
    }

    // ---- grid barrier (graph-capture-safe; counter memset to 0 pre-launch) ----
    __syncthreads();            // all lanes' prep stores issued
    __threadfence();            // device-scope release of workspace writes
    if (tid == 0) {
        __hip_atomic_fetch_add(cnt, 1u, __ATOMIC_RELEASE, __HIP_MEMORY_SCOPE_AGENT);
        unsigned int v; int spins = 0;
        do {
            v = __hip_atomic_load(cnt, __ATOMIC_ACQUIRE, __HIP_MEMORY_SCOPE_AGENT);
        } while (v < (unsigned)NBLOCKS && ++spins < (1 << 23));
    }
    __syncthreads();
    __threadfence();            // acquire: invalidate L1/L2 before reading ws

    // ---- phase 2: GEMM, identical to R5 ----
    // OUT(16384x768 fp32) = (x ⊙ W) @ GT^T + bias
    // 128x128 tile, BK=64, 4 waves 2x2 (wave tile 64x64), 4x4 frags 16x16x32 f16,
    // XOR-swizzled LDS (0 bank conflicts), global_load_lds width-16 staging.
    {
        _Float16* Ws = smem;
        _Float16* Bs = smem + 128 * 64;
        const _Float16* xbh = (const _Float16*)xb;
        const _Float16* Wbh = (const _Float16*)wb;
        const _Float16* GTh = (const _Float16*)GT;

        const int w_   = tid >> 6;
        const int l    = tid & 63;
        const int quad = l >> 4;
        const int ln   = l & 15;
        const int wr   = w_ >> 1;
        const int wc   = w_ & 1;

        const int ct = bid % 6;          // col tile (768/128)
        const int rt = bid / 6;          // row tile (16384/128)
        const int b  = rt >> 1;          // batch element (tile spans one b)
        const int p0 = (rt & 1) * 128;   // pathway base

        // staging: pass p covers rows p*32..+31; wave w rows w*8..+7 within.
        // LDS slot (row, c) holds global chunk c ^ (row&7)  [XOR swizzle].
        const int srow   = l >> 3;
        const int schunk = (l & 7) ^ srow;
        const _Float16* Wg = Wbh + (size_t)(p0 + w_ * 8 + srow) * KPAD + schunk * 8;
        const _Float16* Bg = GTh + (size_t)(ct * 128 + w_ * 8 + srow) * KPAD + schunk * 8;
        _Float16* WsW = Ws + w_ * 512;
        _Float16* BsW = Bs + w_ * 512;
        const _Float16* xg = xbh + (size_t)b * KPAD + quad * 8;

        f32x4 acc[4][4] = {};

        for (int ks = 0; ks < KSTEPS; ++ks) {
#pragma unroll
            for (int p = 0; p < 4; ++p) {
                gload16(Wg + p * 32 * KPAD, WsW + p * 2048);
                gload16(Bg + p * 32 * KPAD, BsW + p * 2048);
            }
            Wg += 64; Bg += 64;

            f16x8 xq0 = *(const f16x8*)xg;          // x[b, k0 + quad*8 ..]
            f16x8 xq1 = *(const f16x8*)(xg + 32);   // x[b, k0+32 + quad*8 ..]
            xg += 64;

            __syncthreads();                        // staging visible

#pragma unroll
            for (int h = 0; h < 2; ++h) {
                const f16x8 xq = h ? xq1 : xq0;
                const int sw = (((h * 4 + quad) ^ (ln & 7)) * 8);

                f16x8 af[4], bfr[4];
#pragma unroll
                for (int i = 0; i < 4; ++i) {
                    f16x8 wf = *(const f16x8*)(Ws + (wr * 64 + i * 16 + ln) * 64 + sw);
                    af[i] = wf * xq;                // v_pk_mul_f16 x4 — no cvts
                }
#pragma unroll
                for (int i = 0; i < 4; ++i)
                    bfr[i] = *(const f16x8*)(Bs + (wc * 64 + i * 16 + ln) * 64 + sw);

#pragma unroll
                for (int mi = 0; mi < 4; ++mi)
#pragma unroll
                    for (int ni = 0; ni < 4; ++ni)
                        acc[mi][ni] = __builtin_amdgcn_mfma_f32_16x16x32_f16(
                            af[mi], bfr[ni], acc[mi][ni], 0, 0, 0);
            }

            __syncthreads();                        // tile consumed
        }

        // epilogue: C/D layout col=ln, row=quad*4+reg (m89/m91-verified)
        const int rbase = rt * 128 + wr * 64 + quad * 4;
        const int cbase = ct * 128 + wc * 64 + ln;
#pragma unroll
        for (int mi = 0; mi < 4; ++mi) {
#pragma unroll
            for (int reg = 0; reg < 4; ++reg) {
                int r = rbase + mi * 16 + reg;
                float bv = bias[r & 255];           // p = r % 256
                size_t ro = (size_t)r * EMB;
#pragma unroll
                for (int ni = 0; ni < 4; ++ni)
                    out[ro + cbase + ni * 16] = acc[mi][ni][reg] + bv;
            }
        }
    }
}

extern "C" void kernel_launch(void* const* d_in, const int* in_sizes, int n_in,
                              void* d_out, int out_size, void* d_ws, size_t ws_size,
                              hipStream_t stream) {
    // inputs (fp32): x(64x2000), weight(256x2000), bias(256), mask(unused), ge(2000x768)
    const float* x    = (const float*)d_in[0];
    const float* wgt  = (const float*)d_in[1];
    const float* bias = (const float*)d_in[2];
    const float* ge   = (const float*)d_in[4];
    float* out = (float*)d_out;

    char* ws = (char*)d_ws;
    unsigned short* xbuf = (unsigned short*)ws;                        // 262144 B
    unsigned short* Wbuf = (unsigned short*)(ws + 262144);             // 1048576 B
    unsigned short* GTb  = (unsigned short*)(ws + 262144 + 1048576);   // 3145728 B
    unsigned int*   cnt  = (unsigned int*)(ws + 4456448);              // 4 B

    hipMemsetAsync(cnt, 0, 4, stream);   // capturable; resets barrier per replay

    fused_kernel<<<NBLOCKS, 256, 0, stream>>>(x, wgt, ge, bias, out,
                                              xbuf, Wbuf, GTb, cnt);
}

// Round 3
// 134.360 us; speedup vs baseline: 2.1873x; 2.1873x over previous
//
#include <hip/hip_runtime.h>
#include <stdint.h>
#include <stddef.h>

// out[b, p*768+e] = sum_d x[b,d]*W[p,d]*GE[d,e] + bias[p]
// == per-b GEMM: OUT_b(256x768) = W(256x2048) @ (diag(x_b) @ GE)(2048x768) + bias
//
// R8: back to 3-kernel graph (R7 proved e2e = sum(dispatches) + ~62us fixed
// harness overhead; the fused grid-barrier cost 170us of cross-XCD atomic
// ping-pong). The GEMM is rebuilt on the 8-phase/counted-vmcnt template
// (T2+T3+T4+T5): BM=256(=one b, all 256 p) x BN=192 x BK=64, grid 64x4=256
// blocks = exactly 1/CU, 512 thr = 8 waves (2Mx4N), LDS 116KB.
// 3 phases/K-tile, 16 MFMA each; raw s_barrier + sched_barrier(0); vmcnt(5)
// gate once per tile (never 0 until epilogue). x multiplied on the B side
// (2 pk_mul frags/phase, not 8); x row staged in LDS so its reads don't
// pollute the vmcnt count. A swizzle chunk^((row>>1)&3) (64B rows),
// B swizzle chunk^(row&7) (proven 0-conflict).
//
// Staging liveness (tile t, dbuf d=t&1): A.kh0 read@p0 -> restage t+2 @p1;
// A.kh1 read@p0,p1 -> @p2; B.nt0 read@p0,p1 -> @p2; B.nt1 read@p0,p1 ->
// @t+1.p0... issue table: p0: B(t+1).nt1,nt2 | p1: A(t+2).kh0 x2 |
// p2: A(t+2).kh1 x2 + B(t+2).nt0. Gate@p2 for t+1: last t+1 call @t.p0,
// 5 calls after it -> vmcnt(5).
//
// Workspace: xb 64x2048 f16 (262144 B) | Wb 256x2048 f16 (1048576 B) |
// GT 768x2048 f16 (3145728 B) = 4,456,448 B total.

#define F_GENES 2000
#define KPAD    2048
#define P_PATH  256
#define EMB     768
#define BATCH   64

typedef _Float16 f16x8 __attribute__((ext_vector_type(8)));
typedef float    f32x4 __attribute__((ext_vector_type(4)));

__device__ __forceinline__ unsigned short f2h(float f) {
    union { _Float16 h; unsigned short s; } v; v.h = (_Float16)f; return v.s;
}

__device__ __forceinline__ void gload16(const void* g, void* l) {
    __builtin_amdgcn_global_load_lds((const __attribute__((address_space(1))) void*)g,
                                     (__attribute__((address_space(3))) void*)l,
                                     16, 0, 0);
}

// K1: pack x (64 rows) + W (256 rows) fp32 -> fp16, K-padded to 2048 w/ zeros.
__global__ void pack_xw_kernel(const float* __restrict__ x,
                               const float* __restrict__ w,
                               unsigned short* __restrict__ xb,
                               unsigned short* __restrict__ wb) {
    int gid = blockIdx.x * 256 + threadIdx.x;
    int row = gid >> 8;
    int s   = gid & 255;
    int d0  = s * 8;
    const float* src;
    unsigned short* dst;
    if (row < BATCH) { src = x + (size_t)row * F_GENES;           dst = xb + (size_t)row * KPAD; }
    else             { src = w + (size_t)(row - BATCH) * F_GENES; dst = wb + (size_t)(row - BATCH) * KPAD; }
    uint4 ov = make_uint4(0u, 0u, 0u, 0u);
    if (s < 250) {
        float4 v0 = *(const float4*)(src + d0);
        float4 v1 = *(const float4*)(src + d0 + 4);
        unsigned short* os = (unsigned short*)&ov;
        os[0] = f2h(v0.x); os[1] = f2h(v0.y); os[2] = f2h(v0.z); os[3] = f2h(v0.w);
        os[4] = f2h(v1.x); os[5] = f2h(v1.y); os[6] = f2h(v1.z); os[7] = f2h(v1.w);
    }
    *(uint4*)(dst + d0) = ov;
}

// K2: GT[n,k] = f16(GE[k,n]), k-padded to 2048.
__global__ void transpose_ge_kernel(const float* __restrict__ ge,
                                    unsigned short* __restrict__ GT) {
    __shared__ unsigned short tile[64][40];
    int kt = blockIdx.x & 63;
    int nt = blockIdx.x >> 6;
    int k0 = kt * 32, n0 = nt * 64;
    int t  = threadIdx.x;
    int kr = t >> 4;
    int nc = (t & 15) * 4;
#pragma unroll
    for (int p = 0; p < 2; ++p) {
        int k = k0 + p * 16 + kr;
        float4 v = make_float4(0.f, 0.f, 0.f, 0.f);
        if (k < F_GENES) v = *(const float4*)(ge + (size_t)k * EMB + n0 + nc);
        int kk = p * 16 + kr;
        tile[nc + 0][kk] = f2h(v.x);
        tile[nc + 1][kk] = f2h(v.y);
        tile[nc + 2][kk] = f2h(v.z);
        tile[nc + 3][kk] = f2h(v.w);
    }
    __syncthreads();
    int n  = t >> 2;
    int kc = (t & 3) * 8;
    uint4 o;
    unsigned short* os = (unsigned short*)&o;
#pragma unroll
    for (int j = 0; j < 8; ++j) os[j] = tile[n][kc + j];
    *(uint4*)(GT + (size_t)(n0 + n) * KPAD + k0 + kc) = o;
}

// ---- GEMM: 256x192 tile, 3-phase deep pipeline, counted vmcnt ----
// LDS layout (f16 units):
//   A: [2 dbuf][2 kh][256 row][32]  off 0,      32768 f16 (64 KB)
//   B: [2 dbuf][192 row][64]        off 32768,  24576 f16 (48 KB)
//   X: [2048]                       off 57344,   2048 f16 (4 KB)
#define A_OFF 0
#define B_OFF 32768
#define X_OFF 57344

#define SBAR() __builtin_amdgcn_sched_barrier(0)
#define BAR()  do { SBAR(); __builtin_amdgcn_s_barrier(); SBAR(); } while (0)

__global__ __launch_bounds__(512, 2)
void gemm_kernel(const _Float16* __restrict__ xb, const _Float16* __restrict__ Wb,
                 const _Float16* __restrict__ GT, const float* __restrict__ bias,
                 float* __restrict__ out) {
    __shared__ __align__(16) _Float16 smem[59392];   // 116 KB

    const int tid  = threadIdx.x;
    const int wid  = tid >> 6;
    const int l    = tid & 63;
    const int quad = l >> 4;
    const int ln   = l & 15;
    const int wm   = wid >> 2;     // 0..1  (M half)
    const int wn   = wid & 3;      // 0..3  (16-col group within each 64-col nf)

    const int ct = blockIdx.x & 3;    // 768 / 192
    const int b  = blockIdx.x >> 2;   // batch element

    // staging thread->element maps
    const int a_lr   = tid >> 2;      // 0..127 (row within 128-row group)
    const int a_slot = tid & 3;       // 16B slot in 64B row
    const int b_lr   = tid >> 3;      // 0..63
    const int b_slot = tid & 7;       // 16B slot in 128B row

    // A stage: rows g*128..+128 of W, kh-plane, tile kt -> A[d][kh]
#define STAGE_A(d, kh, g, kt) do {                                             \
    int row_ = (g) * 128 + a_lr;                                               \
    gload16(Wb + (size_t)row_ * KPAD + (kt) * 64 + (kh) * 32                   \
                + ((a_slot ^ ((row_ >> 1) & 3)) * 8),                          \
            smem + A_OFF + ((d) * 2 + (kh)) * 8192 + ((g) * 128 + wid * 16) * 32); \
} while (0)

    // B stage: rows j*64..+64 of GT (n = ct*192 + row), tile kt -> B[d]
#define STAGE_B(d, j, kt) do {                                                 \
    int row_ = (j) * 64 + b_lr;                                                \
    gload16(GT + (size_t)(ct * 192 + row_) * KPAD + (kt) * 64                  \
                + ((b_slot ^ (row_ & 7)) * 8),                                 \
            smem + B_OFF + (d) * 12288 + ((j) * 64 + wid * 8) * 64);           \
} while (0)

    // fragment reads (swizzled)
#define READ_A(d, kh, mf) (*(const f16x8*)(smem + A_OFF                        \
    + ((d) * 2 + (kh)) * 8192 + (wm * 128 + (mf) * 16 + ln) * 32               \
    + ((quad ^ ((ln >> 1) & 3)) * 8)))
#define READ_B(d, j, kh) (*(const f16x8*)(smem + B_OFF                         \
    + (d) * 12288 + ((j) * 64 + wn * 16 + ln) * 64                             \
    + ((((kh) * 4 + quad) ^ (ln & 7)) * 8)))
#define READ_X(kh, t) (*(const f16x8*)(smem + X_OFF + (t) * 64 + (kh) * 32 + quad * 8))

    // ---- stage x row (b) into LDS; lgkm-counted, keeps vmcnt bookkeeping clean
    if (tid < 256) {
        f16x8 v = *(const f16x8*)(xb + (size_t)b * KPAD + tid * 8);
        *(f16x8*)(smem + X_OFF + tid * 8) = v;
    }
    __syncthreads();   // full drain OK here: no gloads in flight yet

    f32x4 acc[8][3];
#pragma unroll
    for (int i = 0; i < 8; ++i)
#pragma unroll
        for (int j = 0; j < 3; ++j)
            acc[i][j] = (f32x4){0.f, 0.f, 0.f, 0.f};

    // ---- prologue: tile0 full (7 calls) + tile1 minus B.nt1/nt2 (5 calls)
    STAGE_A(0, 0, 0, 0); STAGE_A(0, 0, 1, 0); STAGE_A(0, 1, 0, 0); STAGE_A(0, 1, 1, 0);
    STAGE_B(0, 0, 0);    STAGE_B(0, 1, 0);    STAGE_B(0, 2, 0);
    STAGE_A(1, 0, 0, 1); STAGE_A(1, 0, 1, 1); STAGE_A(1, 1, 0, 1); STAGE_A(1, 1, 1, 1);
    STAGE_B(1, 0, 1);
    asm volatile("s_waitcnt vmcnt(5)" ::: "memory");   // tile0 landed; tile1's 5 in flight
    BAR();

    for (int t = 0; t < 32; ++t) {
        const int d  = t & 1;
        const int dn = d ^ 1;
        f16x8 af0[8], af1[8];

        // ======== phase 0: kh0 x {nf0, nf1} ========
#pragma unroll
        for (int mf = 0; mf < 8; ++mf) af0[mf] = READ_A(d, 0, mf);
        f16x8 xq0 = READ_X(0, t);
        f16x8 bf00 = READ_B(d, 0, 0) * xq0;
        f16x8 bf10 = READ_B(d, 1, 0) * xq0;
        if (t + 1 < 32) { STAGE_B(dn, 1, t + 1); STAGE_B(dn, 2, t + 1); }
        BAR();
        __builtin_amdgcn_s_setprio(1);
#pragma unroll
        for (int mf = 0; mf < 8; ++mf) {
            acc[mf][0] = __builtin_amdgcn_mfma_f32_16x16x32_f16(af0[mf], bf00, acc[mf][0], 0, 0, 0);
            acc[mf][1] = __builtin_amdgcn_mfma_f32_16x16x32_f16(af0[mf], bf10, acc[mf][1], 0, 0, 0);
        }
        __builtin_amdgcn_s_setprio(0);
        BAR();

        // ======== phase 1: kh1 x {nf0, nf1} ========
#pragma unroll
        for (int mf = 0; mf < 8; ++mf) af1[mf] = READ_A(d, 1, mf);
        f16x8 xq1 = READ_X(1, t);
        f16x8 bf01 = READ_B(d, 0, 1) * xq1;
        f16x8 bf11 = READ_B(d, 1, 1) * xq1;
        if (t + 2 < 32) { STAGE_A(d, 0, 0, t + 2); STAGE_A(d, 0, 1, t + 2); }
        BAR();
        __builtin_amdgcn_s_setprio(1);
#pragma unroll
        for (int mf = 0; mf < 8; ++mf) {
            acc[mf][0] = __builtin_amdgcn_mfma_f32_16x16x32_f16(af1[mf], bf01, acc[mf][0], 0, 0, 0);
            acc[mf][1] = __builtin_amdgcn_mfma_f32_16x16x32_f16(af1[mf], bf11, acc[mf][1], 0, 0, 0);
        }
        __builtin_amdgcn_s_setprio(0);
        BAR();

        // ======== phase 2: {kh0, kh1} x nf2 ========
        f16x8 bf20 = READ_B(d, 2, 0) * xq0;
        f16x8 bf21 = READ_B(d, 2, 1) * xq1;
        if (t + 2 < 32) { STAGE_A(d, 1, 0, t + 2); STAGE_A(d, 1, 1, t + 2); STAGE_B(d, 0, t + 2); }
        if (t >= 30) asm volatile("s_waitcnt vmcnt(0)" ::: "memory");
        else         asm volatile("s_waitcnt vmcnt(5)" ::: "memory");
        BAR();
        __builtin_amdgcn_s_setprio(1);
#pragma unroll
        for (int mf = 0; mf < 8; ++mf) {
            acc[mf][2] = __builtin_amdgcn_mfma_f32_16x16x32_f16(af0[mf], bf20, acc[mf][2], 0, 0, 0);
            acc[mf][2] = __builtin_amdgcn_mfma_f32_16x16x32_f16(af1[mf], bf21, acc[mf][2], 0, 0, 0);
        }
        __builtin_amdgcn_s_setprio(0);
        BAR();
    }

    // ---- epilogue: C/D layout col=ln, row=quad*4+reg
    const size_t obase = (size_t)b * P_PATH * EMB;
#pragma unroll
    for (int mf = 0; mf < 8; ++mf) {
#pragma unroll
        for (int reg = 0; reg < 4; ++reg) {
            int p = wm * 128 + mf * 16 + quad * 4 + reg;
            float bv = bias[p];
            size_t ro = obase + (size_t)p * EMB + ct * 192 + wn * 16 + ln;
            out[ro +   0] = acc[mf][0][reg] + bv;
            out[ro +  64] = acc[mf][1][reg] + bv;
            out[ro + 128] = acc[mf][2][reg] + bv;
        }
    }
}

extern "C" void kernel_launch(void* const* d_in, const int* in_sizes, int n_in,
                              void* d_out, int out_size, void* d_ws, size_t ws_size,
                              hipStream_t stream) {
    // inputs (fp32): x(64x2000), weight(256x2000), bias(256), mask(unused), ge(2000x768)
    const float* x    = (const float*)d_in[0];
    const float* wgt  = (const float*)d_in[1];
    const float* bias = (const float*)d_in[2];
    const float* ge   = (const float*)d_in[4];
    float* out = (float*)d_out;

    char* ws = (char*)d_ws;
    unsigned short* xbuf = (unsigned short*)ws;                        // 262144 B
    unsigned short* Wbuf = (unsigned short*)(ws + 262144);             // 1048576 B
    unsigned short* GTb  = (unsigned short*)(ws + 262144 + 1048576);   // 3145728 B

    pack_xw_kernel<<<((BATCH + P_PATH) * 256) / 256, 256, 0, stream>>>(x, wgt, xbuf, Wbuf);
    transpose_ge_kernel<<<64 * 12, 256, 0, stream>>>(ge, GTb);
    gemm_kernel<<<dim3(64 * 4), dim3(512), 0, stream>>>(
        (const _Float16*)xbuf, (const _Float16*)Wbuf, (const _Float16*)GTb, bias, out);
}

// Round 4
// 128.150 us; speedup vs baseline: 2.2932x; 1.0485x over previous
//
#include <hip/hip_runtime.h>
#include <stdint.h>
#include <stddef.h>

// out[b, p*768+e] = sum_d x[b,d]*W[p,d]*GE[d,e] + bias[p]
// == per-b GEMM: OUT_b(256x768) = (diag-x-scaled W)(256x2048) @ GT^T + bias
//
// R9 vs R8: R8's 3-phase 256x192 was LDS-read-bound (26 b128/48 MFMA/wave =
// ratio 1.34) with lockstep windows -> 31% MfmaUtil. R9 rebalances:
// BM=128 x BN=192 x BK=64, 256 thr (4 waves 2x2), wave tile 64x96 ->
// 20 b128/48 MFMA = ratio ~1.0, AND LDS trimmed to exactly 80 KB so TWO
// blocks co-reside per CU (grid 512 = 2 x 256 CUs, full fill). The two
// blocks' barrier phases desync -> one block's MFMA covers the other's
// read window (overlap the single-block lockstep can't give).
// x multiplied into A-side frags (4 pk_mul-frags/phase), loaded from global
// with depth-1 reg prefetch, counted in the vmcnt gate. 2 phases/tile,
// 4 barriers/tile, counted vmcnt(2) (never 0 until tail).
//
// Staging liveness (tile t, d=t&1): t.p0 issues A(t+1->dn)kh1 x2 +
// B(t+1->dn) x6 (regions last read t-1.p1) + x(t+1) loads; t.p1 issues
// A(t+2->d)kh0 x2 (freed after t.p0). Gate at t.p1: everything for t+1
// is older than the 2 newest -> s_waitcnt vmcnt(2).
//
// Workspace: xb 64x2048 f16 (262144 B) | Wb 256x2048 f16 (1048576 B) |
// GT 768x2048 f16 (3145728 B) = 4,456,448 B total.

#define F_GENES 2000
#define KPAD    2048
#define P_PATH  256
#define EMB     768
#define BATCH   64
#define NT      32        // K tiles of BK=64

typedef _Float16 f16x8 __attribute__((ext_vector_type(8)));
typedef float    f32x4 __attribute__((ext_vector_type(4)));

__device__ __forceinline__ unsigned short f2h(float f) {
    union { _Float16 h; unsigned short s; } v; v.h = (_Float16)f; return v.s;
}

__device__ __forceinline__ void gload16(const void* g, void* l) {
    __builtin_amdgcn_global_load_lds((const __attribute__((address_space(1))) void*)g,
                                     (__attribute__((address_space(3))) void*)l,
                                     16, 0, 0);
}

// K1: pack x (64 rows) + W (256 rows) fp32 -> fp16, K-padded to 2048 w/ zeros.
__global__ void pack_xw_kernel(const float* __restrict__ x,
                               const float* __restrict__ w,
                               unsigned short* __restrict__ xb,
                               unsigned short* __restrict__ wb) {
    int gid = blockIdx.x * 256 + threadIdx.x;
    int row = gid >> 8;
    int s   = gid & 255;
    int d0  = s * 8;
    const float* src;
    unsigned short* dst;
    if (row < BATCH) { src = x + (size_t)row * F_GENES;           dst = xb + (size_t)row * KPAD; }
    else             { src = w + (size_t)(row - BATCH) * F_GENES; dst = wb + (size_t)(row - BATCH) * KPAD; }
    uint4 ov = make_uint4(0u, 0u, 0u, 0u);
    if (s < 250) {
        float4 v0 = *(const float4*)(src + d0);
        float4 v1 = *(const float4*)(src + d0 + 4);
        unsigned short* os = (unsigned short*)&ov;
        os[0] = f2h(v0.x); os[1] = f2h(v0.y); os[2] = f2h(v0.z); os[3] = f2h(v0.w);
        os[4] = f2h(v1.x); os[5] = f2h(v1.y); os[6] = f2h(v1.z); os[7] = f2h(v1.w);
    }
    *(uint4*)(dst + d0) = ov;
}

// K2: GT[n,k] = f16(GE[k,n]), k-padded to 2048.
__global__ void transpose_ge_kernel(const float* __restrict__ ge,
                                    unsigned short* __restrict__ GT) {
    __shared__ unsigned short tile[64][40];
    int kt = blockIdx.x & 63;
    int nt = blockIdx.x >> 6;
    int k0 = kt * 32, n0 = nt * 64;
    int t  = threadIdx.x;
    int kr = t >> 4;
    int nc = (t & 15) * 4;
#pragma unroll
    for (int p = 0; p < 2; ++p) {
        int k = k0 + p * 16 + kr;
        float4 v = make_float4(0.f, 0.f, 0.f, 0.f);
        if (k < F_GENES) v = *(const float4*)(ge + (size_t)k * EMB + n0 + nc);
        int kk = p * 16 + kr;
        tile[nc + 0][kk] = f2h(v.x);
        tile[nc + 1][kk] = f2h(v.y);
        tile[nc + 2][kk] = f2h(v.z);
        tile[nc + 3][kk] = f2h(v.w);
    }
    __syncthreads();
    int n  = t >> 2;
    int kc = (t & 3) * 8;
    uint4 o;
    unsigned short* os = (unsigned short*)&o;
#pragma unroll
    for (int j = 0; j < 8; ++j) os[j] = tile[n][kc + j];
    *(uint4*)(GT + (size_t)(n0 + n) * KPAD + k0 + kc) = o;
}

// ---- GEMM: 128x192 tile, 4 waves, 2 blocks/CU, 2-phase counted-vmcnt ----
// LDS (f16 units): A [2 dbuf][2 kh][128 row][32] @0 (16384 f16 = 32 KB)
//                  B [2 dbuf][192 row][64]      @16384 (24576 f16 = 48 KB)
#define A_OFF 0
#define B_OFF 16384

#define SBAR() __builtin_amdgcn_sched_barrier(0)
#define BAR()  do { SBAR(); __builtin_amdgcn_s_barrier(); SBAR(); } while (0)

__global__ __launch_bounds__(256, 2)
void gemm_kernel(const _Float16* __restrict__ xb, const _Float16* __restrict__ Wb,
                 const _Float16* __restrict__ GT, const float* __restrict__ bias,
                 float* __restrict__ out) {
    __shared__ __align__(16) _Float16 smem[40960];   // 80 KB exactly

    const int tid  = threadIdx.x;
    const int wv   = tid >> 6;        // wave 0..3
    const int l    = tid & 63;
    const int quad = l >> 4;
    const int ln   = l & 15;
    const int wm   = wv >> 1;         // 0..1 (M half: 64 rows)
    const int wn   = wv & 1;          // 0..1 (N half: 96 cols)

    const int ct = blockIdx.x & 3;    // 768 / 192
    const int rt = blockIdx.x >> 2;   // 0..127 (128-row slab of OUT)
    const int ph = (rt & 1) * 128;    // pathway base within W (BM=128 = half a b)
    const int b  = rt >> 1;           // batch element

    // A stage: 64 rows per call (c=0,1), kh-plane, tile kt. Source row of W
    // is ph + row (A rows are (b,p) pairs; W has only 256 rows).
#define STAGE_A(d, kh, c, kt) do {                                             \
    int row_ = (c) * 64 + (tid >> 2);                                          \
    gload16(Wb + (size_t)(ph + row_) * KPAD + (kt) * 64 + (kh) * 32            \
                + (((tid & 3) ^ ((row_ >> 1) & 3)) * 8),                       \
            smem + A_OFF + ((d) * 2 + (kh)) * 4096 + ((c) * 64 + wv * 16) * 32); \
} while (0)

    // B stage: 32 rows per call (c=0..5), tile kt.
#define STAGE_B(d, c, kt) do {                                                 \
    int row_ = (c) * 32 + (tid >> 3);                                          \
    gload16(GT + (size_t)(ct * 192 + row_) * KPAD + (kt) * 64                  \
                + (((tid & 7) ^ (row_ & 7)) * 8),                              \
            smem + B_OFF + (d) * 12288 + ((c) * 32 + wv * 8) * 64);            \
} while (0)

    // fragment reads (swizzle-matched to stages; conflict-free per R5/R8 PMC)
#define READ_A(d, kh, mf) (*(const f16x8*)(smem + A_OFF                        \
    + ((d) * 2 + (kh)) * 4096 + (wm * 64 + (mf) * 16 + ln) * 32               \
    + ((quad ^ ((ln >> 1) & 3)) * 8)))
#define READ_B(d, nf, kh) (*(const f16x8*)(smem + B_OFF                        \
    + (d) * 12288 + (wn * 96 + (nf) * 16 + ln) * 64                           \
    + ((((kh) * 4 + quad) ^ (ln & 7)) * 8)))

    const _Float16* xg = xb + (size_t)b * KPAD + quad * 8;   // + t*64 + kh*32

    f32x4 acc[4][6];
#pragma unroll
    for (int i = 0; i < 4; ++i)
#pragma unroll
        for (int j = 0; j < 6; ++j)
            acc[i][j] = (f32x4){0.f, 0.f, 0.f, 0.f};

    // ---- prologue: tile0 full (10) + x(t0) (2 loads) + tile1 A.kh0 (2) ----
    STAGE_A(0, 0, 0, 0); STAGE_A(0, 0, 1, 0);
    STAGE_A(0, 1, 0, 0); STAGE_A(0, 1, 1, 0);
    STAGE_B(0, 0, 0); STAGE_B(0, 1, 0); STAGE_B(0, 2, 0);
    STAGE_B(0, 3, 0); STAGE_B(0, 4, 0); STAGE_B(0, 5, 0);
    f16x8 xc0 = *(const f16x8*)(xg + 0);
    f16x8 xc1 = *(const f16x8*)(xg + 32);
    STAGE_A(1, 0, 0, 1); STAGE_A(1, 0, 1, 1);
    asm volatile("s_waitcnt vmcnt(2)" ::: "memory");   // t0 + x landed
    BAR();

    f16x8 xn0 = xc0, xn1 = xc1;

    for (int t = 0; t < NT; ++t) {
        const int d  = t & 1;
        const int dn = d ^ 1;
        f16x8 af[4], bf[6];

        // ======== phase 0: kh0 x all 6 nf ========
#pragma unroll
        for (int mf = 0; mf < 4; ++mf) af[mf] = READ_A(d, 0, mf) * xc0;
#pragma unroll
        for (int nf = 0; nf < 6; ++nf) bf[nf] = READ_B(d, nf, 0);
        if (t + 1 < NT) {
            STAGE_A(dn, 1, 0, t + 1); STAGE_A(dn, 1, 1, t + 1);
            STAGE_B(dn, 0, t + 1); STAGE_B(dn, 1, t + 1); STAGE_B(dn, 2, t + 1);
            STAGE_B(dn, 3, t + 1); STAGE_B(dn, 4, t + 1); STAGE_B(dn, 5, t + 1);
            xn0 = *(const f16x8*)(xg + (t + 1) * 64);
            xn1 = *(const f16x8*)(xg + (t + 1) * 64 + 32);
        }
        BAR();
        __builtin_amdgcn_s_setprio(1);
#pragma unroll
        for (int nf = 0; nf < 6; ++nf)
#pragma unroll
            for (int mf = 0; mf < 4; ++mf)
                acc[mf][nf] = __builtin_amdgcn_mfma_f32_16x16x32_f16(
                    af[mf], bf[nf], acc[mf][nf], 0, 0, 0);
        __builtin_amdgcn_s_setprio(0);
        BAR();

        // ======== phase 1: kh1 x all 6 nf ========
#pragma unroll
        for (int mf = 0; mf < 4; ++mf) af[mf] = READ_A(d, 1, mf) * xc1;
#pragma unroll
        for (int nf = 0; nf < 6; ++nf) bf[nf] = READ_B(d, nf, 1);
        if (t + 2 < NT) {
            STAGE_A(d, 0, 0, t + 2); STAGE_A(d, 0, 1, t + 2);
            asm volatile("s_waitcnt vmcnt(2)" ::: "memory");   // t+1 complete
        } else {
            asm volatile("s_waitcnt vmcnt(0)" ::: "memory");
        }
        BAR();
        __builtin_amdgcn_s_setprio(1);
#pragma unroll
        for (int nf = 0; nf < 6; ++nf)
#pragma unroll
            for (int mf = 0; mf < 4; ++mf)
                acc[mf][nf] = __builtin_amdgcn_mfma_f32_16x16x32_f16(
                    af[mf], bf[nf], acc[mf][nf], 0, 0, 0);
        __builtin_amdgcn_s_setprio(0);
        BAR();

        xc0 = xn0; xc1 = xn1;
    }

    // ---- epilogue: C/D layout col=ln, row=quad*4+reg (m89/m91-verified) ----
#pragma unroll
    for (int mf = 0; mf < 4; ++mf) {
#pragma unroll
        for (int reg = 0; reg < 4; ++reg) {
            int r = rt * 128 + wm * 64 + mf * 16 + quad * 4 + reg;
            float bv = bias[r & 255];
            size_t ro = (size_t)r * EMB + ct * 192 + wn * 96 + ln;
#pragma unroll
            for (int nf = 0; nf < 6; ++nf)
                out[ro + nf * 16] = acc[mf][nf][reg] + bv;
        }
    }
}

extern "C" void kernel_launch(void* const* d_in, const int* in_sizes, int n_in,
                              void* d_out, int out_size, void* d_ws, size_t ws_size,
                              hipStream_t stream) {
    // inputs (fp32): x(64x2000), weight(256x2000), bias(256), mask(unused), ge(2000x768)
    const float* x    = (const float*)d_in[0];
    const float* wgt  = (const float*)d_in[1];
    const float* bias = (const float*)d_in[2];
    const float* ge   = (const float*)d_in[4];
    float* out = (float*)d_out;

    char* ws = (char*)d_ws;
    unsigned short* xbuf = (unsigned short*)ws;                        // 262144 B
    unsigned short* Wbuf = (unsigned short*)(ws + 262144);             // 1048576 B
    unsigned short* GTb  = (unsigned short*)(ws + 262144 + 1048576);   // 3145728 B

    pack_xw_kernel<<<((BATCH + P_PATH) * 256) / 256, 256, 0, stream>>>(x, wgt, xbuf, Wbuf);
    transpose_ge_kernel<<<64 * 12, 256, 0, stream>>>(ge, GTb);
    gemm_kernel<<<dim3(128 * 4), dim3(256), 0, stream>>>(
        (const _Float16*)xbuf, (const _Float16*)Wbuf, (const _Float16*)GTb, bias, out);
}